// Round 15
// baseline (1009.513 us; speedup 1.0000x reference)
//
#include <hip/hip_runtime.h>
#include <hip/hip_fp16.h>
#include <math.h>

#define TPB 256
#define BSHIFT 7                 // 128 nodes per bucket
#define BNODES (1 << BSHIFT)
#define BMAX 1024                // supports n <= 131072
#define CH 4096                  // edges per bin chunk
#define SPAN (4 * CH)            // contiguous edges per bin block (XCD locality)
#define STAGE_CAP 6144           // LDS edge stage per bucket

// ---------- P1: bucket histogram (LDS-privatized) ----------
__global__ __launch_bounds__(256) void hist_kernel(const int2* __restrict__ edges,
                                                   int* __restrict__ bucket_cnt,
                                                   int e, int B) {
    __shared__ int h[BMAX];
    for (int i = threadIdx.x; i < B; i += 256) h[i] = 0;
    __syncthreads();
    for (int t = blockIdx.x * 256 + threadIdx.x; t < e; t += gridDim.x * 256)
        atomicAdd(&h[edges[t].y >> BSHIFT], 1);
    __syncthreads();
    for (int i = threadIdx.x; i < B; i += 256) {
        int c = h[i];
        if (c) atomicAdd(&bucket_cnt[i], c);
    }
}

// ---------- P2: scan bucket counts ----------
__global__ __launch_bounds__(1024) void bscan_kernel(const int* __restrict__ bucket_cnt,
                                                     int* __restrict__ bucket_start,
                                                     int* __restrict__ bucket_cursor,
                                                     int* __restrict__ row_start,
                                                     int n, int e, int B) {
    __shared__ int s[BMAX];
    int t = threadIdx.x;
    s[t] = (t < B) ? bucket_cnt[t] : 0;
    __syncthreads();
    for (int off = 1; off < BMAX; off <<= 1) {
        int v = (t >= off) ? s[t - off] : 0;
        __syncthreads();
        s[t] += v;
        __syncthreads();
    }
    if (t < B) {
        int st = (t > 0) ? s[t - 1] : 0;
        bucket_start[t] = st;
        bucket_cursor[t] = st;
    }
    if (t == 0) { bucket_start[B] = e; row_start[n] = e; }
}

// ---------- P3: bin edges by bucket (block-contiguous spans) ----------
__global__ __launch_bounds__(256) void bin_kernel(const int2* __restrict__ edges,
                                                  int* __restrict__ bucket_cursor,
                                                  unsigned* __restrict__ ebuf,
                                                  int e, int B) {
    __shared__ int h[BMAX];
    long long start = (long long)blockIdx.x * SPAN;
    long long endS = start + SPAN < (long long)e ? start + SPAN : (long long)e;
    for (long long base = start; base < endS; base += CH) {
        int cnt = (int)((endS - base) < CH ? (endS - base) : CH);
        for (int i = threadIdx.x; i < B; i += 256) h[i] = 0;
        __syncthreads();
        for (int t = threadIdx.x; t < cnt; t += 256)
            atomicAdd(&h[edges[base + t].y >> BSHIFT], 1);
        __syncthreads();
        for (int i = threadIdx.x; i < B; i += 256) {
            int c = h[i];
            if (c) h[i] = atomicAdd(&bucket_cursor[i], c);
        }
        __syncthreads();
        for (int t = threadIdx.x; t < cnt; t += 256) {
            int2 sd = edges[base + t];
            int pos = atomicAdd(&h[sd.y >> BSHIFT], 1);
            ebuf[pos] = ((unsigned)(sd.y & (BNODES - 1)) << 17) | (unsigned)sd.x;
        }
        __syncthreads();
    }
}

// ---------- P4: per-bucket finalize: deg/dinv/row_start + csr_src ----------
__global__ __launch_bounds__(256) void finalize_kernel(const unsigned* __restrict__ ebuf,
                                                       const int* __restrict__ bucket_start,
                                                       int* __restrict__ row_start,
                                                       int* __restrict__ csr_src,
                                                       float* __restrict__ dinv, int n) {
    int b = blockIdx.x;
    int s0 = bucket_start[b], s1 = bucket_start[b + 1];
    int cnt = s1 - s0;
    int node0 = b << BSHIFT;
    int nn = min(BNODES, n - node0);
    __shared__ int ldeg[BNODES];
    __shared__ int lcur[BNODES];
    __shared__ int sc[BNODES];
    __shared__ unsigned stage[STAGE_CAP];
    int t = threadIdx.x;
    for (int i = t; i < BNODES; i += 256) ldeg[i] = 0;
    __syncthreads();
    bool uselds = (cnt <= STAGE_CAP);
    for (int tt = t; tt < cnt; tt += 256) {
        unsigned p = ebuf[s0 + tt];
        if (uselds) stage[tt] = p;
        atomicAdd(&ldeg[p >> 17], 1);
    }
    __syncthreads();
    if (t < BNODES) sc[t] = ldeg[t];
    __syncthreads();
    for (int off = 1; off < BNODES; off <<= 1) {
        int v = 0;
        if (t < BNODES && t >= off) v = sc[t - off];
        __syncthreads();
        if (t < BNODES) sc[t] += v;
        __syncthreads();
    }
    if (t < nn) {
        int excl = (t > 0) ? sc[t - 1] : 0;
        row_start[node0 + t] = s0 + excl;
        lcur[t] = s0 + excl;
        dinv[node0 + t] = rsqrtf((float)(ldeg[t] + 1));
    } else if (t < BNODES) {
        lcur[t] = 0;
    }
    __syncthreads();
    for (int tt = t; tt < cnt; tt += 256) {
        unsigned p = uselds ? stage[tt] : ebuf[s0 + tt];
        int pos = atomicAdd(&lcur[p >> 17], 1);
        csr_src[pos] = (int)(p & 0x1FFFFu);
    }
}

// ---------- k-outer channel-split GEMM, PAIR-SLICED outputs ---------------
// 4 waves/block; wave wq computes channels [wq*16, wq*16+16) == channel-pair
// wq. Messages / hidden state live in pair-sliced layout [pair][node][16ch]
// so the aggregate's per-XCD working set is one pair (3.2 MB < 4 MB L2).
// MODE 0: fp16 message pair: Tshp[wq][i][16] = (row @ W)[wq*16..] * dinv[i]
// MODE 1: fp32 hidden pair:  hbufp[wq][i][16] = relu(... + bias)
template <int FIN, int MODE>
__device__ __forceinline__ void accum4(const float4 v, const float* __restrict__ wk,
                                       float* __restrict__ res) {
#pragma unroll
    for (int cc = 0; cc < 16; cc++) res[cc] = fmaf(v.x, wk[cc], res[cc]);
#pragma unroll
    for (int cc = 0; cc < 16; cc++) res[cc] = fmaf(v.y, wk[64 + cc], res[cc]);
#pragma unroll
    for (int cc = 0; cc < 16; cc++) res[cc] = fmaf(v.z, wk[128 + cc], res[cc]);
#pragma unroll
    for (int cc = 0; cc < 16; cc++) res[cc] = fmaf(v.w, wk[192 + cc], res[cc]);
}

template <int FIN, int MODE>
__global__ __launch_bounds__(256) void gemm_node_k(
    const float* __restrict__ x, const float* __restrict__ h,
    const float* __restrict__ W, const float* __restrict__ bias,
    const float* __restrict__ dinv, void* __restrict__ out, int n) {
    int lane = threadIdx.x & 63;
    int wq = __builtin_amdgcn_readfirstlane(threadIdx.x >> 6);  // 0..3, SGPR
    int node0 = blockIdx.x << 6;
    int i = node0 + lane;
    int ic = min(i, n - 1);
    float res[16];
#pragma unroll
    for (int cc = 0; cc < 16; cc++) res[cc] = 0.f;
    const float* Wq = W + wq * 16;               // wave-uniform base
    float xr[FIN];
    const float4* xp = (const float4*)(x + (size_t)ic * 32);
#pragma unroll
    for (int q = 0; q < 8; q++) {
        float4 v = xp[q];
        xr[q * 4] = v.x; xr[q * 4 + 1] = v.y; xr[q * 4 + 2] = v.z; xr[q * 4 + 3] = v.w;
    }
    if (FIN == 96) {   // h is pair-sliced: [pair][node][16]
#pragma unroll
        for (int pp = 0; pp < 4; pp++) {
            const float4* hp = (const float4*)(h + ((size_t)pp * n + ic) * 16);
#pragma unroll
            for (int q = 0; q < 4; q++) {
                float4 v = hp[q];
                xr[32 + pp * 16 + q * 4] = v.x; xr[32 + pp * 16 + q * 4 + 1] = v.y;
                xr[32 + pp * 16 + q * 4 + 2] = v.z; xr[32 + pp * 16 + q * 4 + 3] = v.w;
            }
        }
    }
#pragma unroll
    for (int q = 0; q < 8; q++)
        accum4<FIN, MODE>(make_float4(xr[q*4], xr[q*4+1], xr[q*4+2], xr[q*4+3]),
                          Wq + (size_t)(q * 4) * 64, res);
    if (FIN == 96) {
#pragma unroll
        for (int q = 8; q < 24; q++)
            accum4<FIN, MODE>(make_float4(xr[q*4], xr[q*4+1], xr[q*4+2], xr[q*4+3]),
                              Wq + (size_t)(q * 4) * 64, res);
    }
    if (MODE == 1) __syncthreads();   // in-place safety: all reads consumed
    if (i >= n) return;
    if (MODE == 0) {
        float scale = dinv[ic];
        union { unsigned short us[16]; uint4 v[2]; } u;
#pragma unroll
        for (int cc = 0; cc < 16; cc++)
            u.us[cc] = __half_as_ushort(__float2half(res[cc] * scale));
        uint4* dst = (uint4*)out + ((size_t)wq * n + i) * 2;
        dst[0] = u.v[0];
        dst[1] = u.v[1];
    } else {
        const float* bp = bias + wq * 16;
        float4* dst = (float4*)((float*)out + ((size_t)wq * n + i) * 16);
#pragma unroll
        for (int t4 = 0; t4 < 4; t4++) {
            float4 o;
            o.x = fmaxf(res[t4 * 4 + 0] + bp[t4 * 4 + 0], 0.f);
            o.y = fmaxf(res[t4 * 4 + 1] + bp[t4 * 4 + 1], 0.f);
            o.z = fmaxf(res[t4 * 4 + 2] + bp[t4 * 4 + 2], 0.f);
            o.w = fmaxf(res[t4 * 4 + 3] + bp[t4 * 4 + 3], 0.f);
            dst[t4] = o;
        }
    }
}

// ---------- pair-sliced pull aggregation over fp16 messages ----------
// pair = blockIdx.x & 3 -> with round-robin block->XCD dispatch each XCD
// touches ONE pair buffer (3.2 MB < 4 MB L2) => gathers become L2 hits.
// 1 thread/node/pair; 32 B per edge per thread; unroll 2 (4 uint4 in flight).
__device__ __forceinline__ void acc8(const uint4 v, float* a) {
    float2 f;
    f = __half22float2(*(const __half2*)&v.x); a[0] += f.x; a[1] += f.y;
    f = __half22float2(*(const __half2*)&v.y); a[2] += f.x; a[3] += f.y;
    f = __half22float2(*(const __half2*)&v.z); a[4] += f.x; a[5] += f.y;
    f = __half22float2(*(const __half2*)&v.w); a[6] += f.x; a[7] += f.y;
}

__global__ __launch_bounds__(256) void aggregate_p(
    const uint4* __restrict__ Tp, const int* __restrict__ row_start,
    const int* __restrict__ csr_src, const float* __restrict__ dinv,
    const float* __restrict__ bias, float* __restrict__ houtp, int n) {
    int p = blockIdx.x & 3;
    int i = (blockIdx.x >> 2) * 256 + threadIdx.x;
    if (i >= n) return;
    size_t pbase = (size_t)p * n;
    float accA[16], accB[16];
#pragma unroll
    for (int k = 0; k < 16; k++) accB[k] = 0.f;
    {   // self loop (already * dinv[i])
        uint4 s0v = Tp[(pbase + i) * 2];
        uint4 s1v = Tp[(pbase + i) * 2 + 1];
        float2 f;
        f = __half22float2(*(const __half2*)&s0v.x); accA[0] = f.x; accA[1] = f.y;
        f = __half22float2(*(const __half2*)&s0v.y); accA[2] = f.x; accA[3] = f.y;
        f = __half22float2(*(const __half2*)&s0v.z); accA[4] = f.x; accA[5] = f.y;
        f = __half22float2(*(const __half2*)&s0v.w); accA[6] = f.x; accA[7] = f.y;
        f = __half22float2(*(const __half2*)&s1v.x); accA[8] = f.x; accA[9] = f.y;
        f = __half22float2(*(const __half2*)&s1v.y); accA[10] = f.x; accA[11] = f.y;
        f = __half22float2(*(const __half2*)&s1v.z); accA[12] = f.x; accA[13] = f.y;
        f = __half22float2(*(const __half2*)&s1v.w); accA[14] = f.x; accA[15] = f.y;
    }
    int s0 = row_start[i], s1 = row_start[i + 1];
    int j = s0;
    for (; j + 2 <= s1; j += 2) {
        int sa = csr_src[j], sb = csr_src[j + 1];
        uint4 va0 = Tp[(pbase + sa) * 2];
        uint4 va1 = Tp[(pbase + sa) * 2 + 1];
        uint4 vb0 = Tp[(pbase + sb) * 2];
        uint4 vb1 = Tp[(pbase + sb) * 2 + 1];
        acc8(va0, accA); acc8(va1, accA + 8);
        acc8(vb0, accB); acc8(vb1, accB + 8);
    }
    if (j < s1) {
        int sa = csr_src[j];
        acc8(Tp[(pbase + sa) * 2], accA);
        acc8(Tp[(pbase + sa) * 2 + 1], accA + 8);
    }
    float di = dinv[i];
    const float* bp = bias + p * 16;
    float4* op = (float4*)(houtp + (pbase + i) * 16);
#pragma unroll
    for (int t4 = 0; t4 < 4; t4++) {
        float4 o;
        o.x = fmaxf((accA[t4 * 4 + 0] + accB[t4 * 4 + 0]) * di + bp[t4 * 4 + 0], 0.f);
        o.y = fmaxf((accA[t4 * 4 + 1] + accB[t4 * 4 + 1]) * di + bp[t4 * 4 + 1], 0.f);
        o.z = fmaxf((accA[t4 * 4 + 2] + accB[t4 * 4 + 2]) * di + bp[t4 * 4 + 2], 0.f);
        o.w = fmaxf((accA[t4 * 4 + 3] + accB[t4 * 4 + 3]) * di + bp[t4 * 4 + 3], 0.f);
        op[t4] = o;
    }
}

// ---------- final head: sigmoid(concat(x,h5) @ Wl2 + bl2), sliced h5 -------
__global__ __launch_bounds__(256) void final_kernel(
    const float* __restrict__ x, const float* __restrict__ h5p,
    const float* __restrict__ Wl2, const float* __restrict__ bl2,
    float* __restrict__ out, int n) {
    int i = blockIdx.x * TPB + threadIdx.x;
    if (i >= n) return;
    float acc = bl2[0];
#pragma unroll
    for (int k = 0; k < 32; k++) acc = fmaf(x[(size_t)i * 32 + k], Wl2[k], acc);
#pragma unroll
    for (int p = 0; p < 4; p++) {
        const float* hp = h5p + ((size_t)p * n + i) * 16;
#pragma unroll
        for (int k = 0; k < 16; k++)
            acc = fmaf(hp[k], Wl2[32 + p * 16 + k], acc);
    }
    out[i] = 1.f / (1.f + expf(-acc));
}

extern "C" void kernel_launch(void* const* d_in, const int* in_sizes, int n_in,
                              void* d_out, int out_size, void* d_ws, size_t ws_size,
                              hipStream_t stream) {
    const float* x   = (const float*)d_in[0];
    const int*   edg = (const int*)d_in[1];
    const float* W1  = (const float*)d_in[2];
    const float* b1  = (const float*)d_in[3];
    const float* W2  = (const float*)d_in[4];
    const float* b2  = (const float*)d_in[5];
    const float* W3  = (const float*)d_in[6];
    const float* b3  = (const float*)d_in[7];
    const float* W4  = (const float*)d_in[8];
    const float* b4  = (const float*)d_in[9];
    const float* Wl1 = (const float*)d_in[10];
    const float* bl1 = (const float*)d_in[11];
    const float* Wl2 = (const float*)d_in[12];
    const float* bl2 = (const float*)d_in[13];
    int n = in_sizes[0] / 32;
    int e = in_sizes[1] / 2;
    int B = (n + BNODES - 1) >> BSHIFT;

    char* ws = (char*)d_ws;
    size_t off = 0;
    auto take = [&](size_t bytes) {
        char* p = ws + off;
        off = (off + bytes + 255) & ~(size_t)255;
        return p;
    };
    int*   bucket_cnt    = (int*)take((size_t)B * 4);
    int*   bucket_start  = (int*)take((size_t)(B + 1) * 4);
    int*   bucket_cursor = (int*)take((size_t)B * 4);
    int*   row_start     = (int*)take((size_t)(n + 1) * 4);
    int*   csr_src       = (int*)take((size_t)e * 4);
    float* dinv          = (float*)take((size_t)n * 4);
    unsigned* Tshp       = (unsigned*)take((size_t)n * 64 * 2);  // fp16 msgs, pair-sliced
    float* hbufp         = (float*)take((size_t)n * 64 * 4);     // fp32 hidden, pair-sliced
    unsigned* ebuf = (unsigned*)Tshp;  // alias (e*4 == n*128); consumed before gemm1

    hipMemsetAsync(bucket_cnt, 0, (size_t)B * 4, stream);

    int nb = (n + TPB - 1) / TPB;
    int nspans = (e + SPAN - 1) / SPAN;
    hist_kernel<<<512, 256, 0, stream>>>((const int2*)edg, bucket_cnt, e, B);
    bscan_kernel<<<1, 1024, 0, stream>>>(bucket_cnt, bucket_start, bucket_cursor,
                                         row_start, n, e, B);
    bin_kernel<<<nspans, 256, 0, stream>>>((const int2*)edg, bucket_cursor, ebuf, e, B);
    finalize_kernel<<<B, 256, 0, stream>>>(ebuf, bucket_start, row_start, csr_src, dinv, n);

    int gb = (n + 63) / 64;            // gemm: 64 nodes, 4 waves x 16 ch
    int ab = 4 * ((n + 255) / 256);    // aggregate: pair = bid&3 (XCD-resident)

    gemm_node_k<32, 0><<<gb, TPB, 0, stream>>>(x, nullptr, W1, nullptr, dinv, Tshp, n);
    aggregate_p<<<ab, TPB, 0, stream>>>((const uint4*)Tshp, row_start, csr_src, dinv, b1, hbufp, n);
    gemm_node_k<96, 0><<<gb, TPB, 0, stream>>>(x, hbufp, W2, nullptr, dinv, Tshp, n);
    aggregate_p<<<ab, TPB, 0, stream>>>((const uint4*)Tshp, row_start, csr_src, dinv, b2, hbufp, n);
    gemm_node_k<96, 0><<<gb, TPB, 0, stream>>>(x, hbufp, W3, nullptr, dinv, Tshp, n);
    aggregate_p<<<ab, TPB, 0, stream>>>((const uint4*)Tshp, row_start, csr_src, dinv, b3, hbufp, n);
    gemm_node_k<96, 0><<<gb, TPB, 0, stream>>>(x, hbufp, W4, nullptr, dinv, Tshp, n);
    aggregate_p<<<ab, TPB, 0, stream>>>((const uint4*)Tshp, row_start, csr_src, dinv, b4, hbufp, n);
    // lin1 in-place on sliced hbufp: reads all pairs, barrier, writes own pair
    gemm_node_k<96, 1><<<gb, TPB, 0, stream>>>(x, hbufp, Wl1, bl1, dinv, hbufp, n);
    final_kernel<<<nb, TPB, 0, stream>>>(x, hbufp, Wl2, bl2, (float*)d_out, n);
}